// Round 20
// baseline (59.406 us; speedup 1.0000x reference)
//
#include <hip/hip_runtime.h>

// SSIM loss, fused. in: f32 (16,3,512,512) x2; out: f32[16].
//
// r20 = r15/r19's per-wave code VERBATIM (92 VGPR, OLD-early STEP order),
// repacked WPB=6 (384-thr blocks, 48KB LDS = 6 wave-private 8KB slices,
// still ZERO barriers) x RPS=6 (84 strips/img = exactly 14 blocks/img).
// Rationale: 19 rounds show occupancy tracks waves-per-block (r2 5-wave:
// 48%, r3 4-wave: 45%; every 1-wave round <=26%), and 1-wave-block
// residency is hard-capped ~5 waves/CU regardless of grid size (r19
// single-variable test). 672 blocks -> ~2.7 blocks/CU x 6 waves ~= 16
// waves/CU (3x r15's residency) at +35% load amp (XCD-pinned L2 absorbs).
//
// Per-wave structure (unchanged): full-width wave, 8 cols/lane; vertical
// sliding column sums {s1,s2,sp,sq} in regs; NEW 3-deep / OLD 2-deep named
// slots; per STEP publish 8 col-quads to sigma-permuted wave-private LDS,
// 10 b128 halo reads, in-register window slide, scale-folded SSIM;
// XCD-pinned img%8 band-major; banked double atomics + finalize.

namespace {
constexpr int BATCH = 16;
constexpr int CHAN  = 3;
constexpr int HDIM  = 512;
constexpr int WDIM  = 512;
constexpr int WIN   = 11;
constexpr int HO    = HDIM - WIN + 1;   // 502
constexpr int WO    = WDIM - WIN + 1;   // 502
constexpr int RPS   = 6;
constexpr int NSTRIP = 84;              // 84*6=504 >= 502; strip83: 4 rows
constexpr int WPB   = 6;
constexpr int NTHR  = WPB * 64;         // 384
constexpr int SBLK  = NSTRIP / WPB;     // 14 blocks per image, exact
constexpr int NIMG  = BATCH * CHAN;     // 48
constexpr int NBLK  = NIMG * SBLK;      // 672
constexpr int NBANK = 16;
// scale-folded constants: C*121^2 (121^4 cancels in n/d)
constexpr float K1 = 6.5025f  * 14641.0f;
constexpr float K2 = 58.5225f * 14641.0f;
constexpr float W2F = 121.0f;
}

__global__ __launch_bounds__(NTHR) void ssim_main(
    const float* __restrict__ g1, const float* __restrict__ g2,
    double* __restrict__ ws) {
  __shared__ float4 Qs[WPB * 512];       // 48 KB: 8KB wave-private slices

  const int t  = threadIdx.x & 63;       // lane 0..63
  const int wv = threadIdx.x >> 6;       // wave 0..5
  // XCD-pinned decode: img%8 == blockIdx%8; band-major within XCD
  const int xcd  = blockIdx.x & 7;
  const int q    = blockIdx.x >> 3;      // 0..83
  const int g    = q % (NIMG / 8);       // 0..5  (image within XCD, fast)
  const int sblk = q / (NIMG / 8);       // 0..13 (band, slow)
  const int img  = g * 8 + xcd;          // 0..47
  const int b    = img / CHAN;

  const int strip = sblk * WPB + wv;     // 0..83
  const int r0 = strip * RPS;
  const int r1 = min(r0 + RPS, HO);      // strip83: 498..501
  const int c0 = 8 * t;                  // lane's first col
  const int tp1 = (t + 1) & 63;          // halo lanes (wrap -> masked outputs)
  const int tp2 = (t + 2) & 63;
  float4* __restrict__ Q = Qs + wv * 512;

  const float* __restrict__ p1 = g1 + (size_t)img * HDIM * WDIM + c0;
  const float* __restrict__ p2 = g2 + (size_t)img * HDIM * WDIM + c0;

  // vertical sliding column sums for the lane's 8 columns
  float s1[8], s2[8], sp[8], sq[8];
#pragma unroll
  for (int k = 0; k < 8; ++k) s1[k] = s2[k] = sp[k] = sq[k] = 0.f;

  // named row-buffer slots: NEW 3-deep (n0,n1,n2), OLD 2-deep (o0,o1)
#define DECL_SLOT(p) float4 p##u0, p##u1, p##v0, p##v1;
  DECL_SLOT(n0) DECL_SLOT(n1) DECL_SLOT(n2) DECL_SLOT(o0) DECL_SLOT(o1)

#define LD(p, row)                                          \
  {                                                         \
    const float* q1_ = p1 + (size_t)(row) * WDIM;           \
    const float* q2_ = p2 + (size_t)(row) * WDIM;           \
    p##u0 = *(const float4*)q1_;                            \
    p##u1 = *(const float4*)(q1_ + 4);                      \
    p##v0 = *(const float4*)q2_;                            \
    p##v1 = *(const float4*)(q2_ + 4);                      \
  }

#define ACC8(p)                                                          \
  {                                                                      \
    float uu[8] = {p##u0.x, p##u0.y, p##u0.z, p##u0.w,                   \
                   p##u1.x, p##u1.y, p##u1.z, p##u1.w};                  \
    float vv[8] = {p##v0.x, p##v0.y, p##v0.z, p##v0.w,                   \
                   p##v1.x, p##v1.y, p##v1.z, p##v1.w};                  \
    _Pragma("unroll") for (int k_ = 0; k_ < 8; ++k_) {                   \
      float x = uu[k_], y = vv[k_];                                      \
      s1[k_] += x;                                                       \
      s2[k_] += y;                                                       \
      sp[k_] = fmaf(x, y, sp[k_]);                                       \
      sq[k_] = fmaf(x, x, sq[k_]);                                       \
      sq[k_] = fmaf(y, y, sq[k_]);                                       \
    }                                                                    \
  }

#define SUB8(p)                                                          \
  {                                                                      \
    float uu[8] = {p##u0.x, p##u0.y, p##u0.z, p##u0.w,                   \
                   p##u1.x, p##u1.y, p##u1.z, p##u1.w};                  \
    float vv[8] = {p##v0.x, p##v0.y, p##v0.z, p##v0.w,                   \
                   p##v1.x, p##v1.y, p##v1.z, p##v1.w};                  \
    _Pragma("unroll") for (int k_ = 0; k_ < 8; ++k_) {                   \
      float x = uu[k_], y = vv[k_];                                      \
      s1[k_] -= x;                                                       \
      s2[k_] -= y;                                                       \
      sp[k_] = fmaf(x, -y, sp[k_]);                                      \
      sq[k_] = fmaf(x, -x, sq[k_]);                                      \
      sq[k_] = fmaf(y, -y, sq[k_]);                                      \
    }                                                                    \
  }

  // ---- warm-up: accumulate rows r0..r0+9, 3-deep pipeline ----
  // (max row touched: r0+12 = 510 at the last strip; in-bounds)
  LD(n0, r0) LD(n1, r0 + 1) LD(n2, r0 + 2)
  ACC8(n0) LD(n0, r0 + 3)
  ACC8(n1) LD(n1, r0 + 4)
  ACC8(n2) LD(n2, r0 + 5)
  ACC8(n0) LD(n0, r0 + 6)
  ACC8(n1) LD(n1, r0 + 7)
  ACC8(n2) LD(n2, r0 + 8)
  ACC8(n0) LD(n0, r0 + 9)
  ACC8(n1) LD(n1, r0 + 10)
  ACC8(n2) LD(n2, r0 + 11)
  ACC8(n0) LD(n0, r0 + 12)
  // accumulated rows r0..r0+9; n1=r0+10, n2=r0+11, n0=r0+12
  LD(o0, r0) LD(o1, r0 + 1)   // OLD 2-deep

  float acc = 0.f;

  // one STEP: NEW slot pn holds row r+10; OLD slot po holds row r.
#define DOSTEP(pn, po, r_)                                               \
  {                                                                      \
    const int rr = (r_);                                                 \
    ACC8(pn)                            /* window = rows [rr, rr+10] */  \
    LD(pn, min(rr + 13, HDIM - 1))      /* NEW for STEP rr+3 */          \
    _Pragma("unroll") for (int i_ = 0; i_ < 8; ++i_)                     \
        Q[i_ * 64 + t] = make_float4(s1[i_], s2[i_], sp[i_], sq[i_]);    \
    asm volatile("s_waitcnt lgkmcnt(0)" ::: "memory");                   \
    float4 h[10];                                                        \
    _Pragma("unroll") for (int m_ = 0; m_ < 8; ++m_)                     \
        h[m_] = Q[m_ * 64 + tp1];                                        \
    h[8] = Q[tp2];                                                       \
    h[9] = Q[64 + tp2];                                                  \
    float w1 = ((s1[0] + s1[1]) + (s1[2] + s1[3])) +                     \
               ((s1[4] + s1[5]) + (s1[6] + s1[7])) +                     \
               ((h[0].x + h[1].x) + h[2].x);                             \
    float w2 = ((s2[0] + s2[1]) + (s2[2] + s2[3])) +                     \
               ((s2[4] + s2[5]) + (s2[6] + s2[7])) +                     \
               ((h[0].y + h[1].y) + h[2].y);                             \
    float wp = ((sp[0] + sp[1]) + (sp[2] + sp[3])) +                     \
               ((sp[4] + sp[5]) + (sp[6] + sp[7])) +                     \
               ((h[0].z + h[1].z) + h[2].z);                             \
    float wq = ((sq[0] + sq[1]) + (sq[2] + sq[3])) +                     \
               ((sq[4] + sq[5]) + (sq[6] + sq[7])) +                     \
               ((h[0].w + h[1].w) + h[2].w);                             \
    _Pragma("unroll") for (int j_ = 0; j_ < 8; ++j_) {                   \
      if (j_ > 0) {                                                      \
        w1 = (w1 - s1[j_ - 1]) + h[j_ + 2].x;                            \
        w2 = (w2 - s2[j_ - 1]) + h[j_ + 2].y;                            \
        wp = (wp - sp[j_ - 1]) + h[j_ + 2].z;                            \
        wq = (wq - sq[j_ - 1]) + h[j_ + 2].w;                            \
      }                                                                  \
      float s12 = w1 * w2;                                               \
      float msq = fmaf(w1, w1, w2 * w2);                                 \
      float N1_ = fmaf(2.f, s12, K1);                                    \
      float N2_ = fmaf(2.f, fmaf(W2F, wp, -s12), K2);                    \
      float D1_ = msq + K1;                                              \
      float D2_ = fmaf(W2F, wq, -msq) + K2;                              \
      float val = (N1_ * N2_) * __builtin_amdgcn_rcpf(D1_ * D2_);        \
      acc += (c0 + j_ < WO) ? val : 0.f;                                 \
    }                                                                    \
    SUB8(po)                            /* remove row rr */              \
    LD(po, rr + 2)                      /* OLD for STEP rr+2 (<=503) */  \
  }

  // main loop: 6 STEPs; NEW cycles n1,n2,n0; OLD alternates o0,o1
  {
    const int r = r0;
    DOSTEP(n1, o0, r)
    if (r + 1 < r1) DOSTEP(n2, o1, r + 1)
    if (r + 2 < r1) DOSTEP(n0, o0, r + 2)
    if (r + 3 < r1) DOSTEP(n1, o1, r + 3)
    if (r + 4 < r1) DOSTEP(n2, o0, r + 4)
    if (r + 5 < r1) DOSTEP(n0, o1, r + 5)
  }
#undef DOSTEP
#undef SUB8
#undef ACC8
#undef LD
#undef DECL_SLOT

  // wave reduction, banked double atomic
#pragma unroll
  for (int off = 32; off > 0; off >>= 1) acc += __shfl_down(acc, off, 64);
  if (t == 0)
    atomicAdd(&ws[b * NBANK + ((blockIdx.x * WPB + wv) & (NBANK - 1))],
              (double)acc);
}

__global__ void ssim_finalize(const double* __restrict__ ws,
                              float* __restrict__ out) {
  int i = threadIdx.x;
  if (i < BATCH) {
    double s = 0.0;
#pragma unroll
    for (int k = 0; k < NBANK; ++k) s += ws[i * NBANK + k];
    out[i] = (float)(1.0 - s / ((double)CHAN * HO * WO));
  }
}

extern "C" void kernel_launch(void* const* d_in, const int* in_sizes, int n_in,
                              void* d_out, int out_size, void* d_ws,
                              size_t ws_size, hipStream_t stream) {
  const float* img1 = (const float*)d_in[0];
  const float* img2 = (const float*)d_in[1];
  float* out = (float*)d_out;
  double* ws = (double*)d_ws;

  hipMemsetAsync(d_ws, 0, BATCH * NBANK * sizeof(double), stream);
  ssim_main<<<dim3(NBLK), NTHR, 0, stream>>>(img1, img2, ws);
  ssim_finalize<<<1, 64, 0, stream>>>(ws, out);
}

// Round 21
// 51.699 us; speedup vs baseline: 1.1491x; 1.1491x over previous
//
#include <hip/hip_runtime.h>

// SSIM loss, fused. in: f32 (16,3,512,512) x2; out: f32[16].
//
// r21 = merge of r3 (highest occupancy ever: 45%, 4-wave cooperative
// blocks, VGPR 36; limited by LDS op count + 5.06M bank conflicts) with
// the champion per-row machinery developed since:
//  * 2 cols/thread, 256 thr/block, 1536 blocks (6/CU x 4 waves).
//  * 4-array quads {s1,s2,sp,sq}: publish 2 b128/thread into
//    double-buffered Qe/Qo[buf][T] (consecutive threads -> consecutive
//    16B: conflict-free), ONE raw (lgkmcnt(0); s_barrier) per row.
//    Double-buffer race argument (r3-proven): reads of buf p at row r
//    complete before that thread's barrier at r+1; next write to p is at
//    r+2, after barrier r+1.
//  * 12 conflict-free b128 halo reads Qe/Qo[min(T+j,255)] (clamped lanes
//    only feed masked cols >= 502); float4 window algebra:
//    W(2T) = (e0+o0)+(e1+o1)+(e2+o2)+(e3+o3)+(e4+o4)+e5;
//    W(2T+1) = W(2T) - e0 + o5.   (11-col windows, verified identity)
//  * NEW rows 2-deep + OLD rows 2-deep in registers, r15 STEP ordering.
//  * Scale-folded SSIM (121^4 cancels), XCD-pinned band-major mapping,
//    banked double atomics + finalize.

namespace {
constexpr int BATCH = 16;
constexpr int CHAN  = 3;
constexpr int HDIM  = 512;
constexpr int WDIM  = 512;
constexpr int WIN   = 11;
constexpr int HO    = HDIM - WIN + 1;   // 502
constexpr int WO    = WDIM - WIN + 1;   // 502
constexpr int RPS   = 16;
constexpr int NSTRIPS = 32;             // strip31: rows 496..501 (6 rows)
constexpr int NTHR  = 256;
constexpr int NIMG  = BATCH * CHAN;     // 48
constexpr int NBLK  = NIMG * NSTRIPS;   // 1536
constexpr int NBANK = 16;
// scale-folded constants: C*121^2 (121^4 cancels in n/d)
constexpr float K1 = 6.5025f  * 14641.0f;
constexpr float K2 = 58.5225f * 14641.0f;
constexpr float W2F = 121.0f;
}

__device__ __forceinline__ float4 f4add(const float4& a, const float4& b) {
  return make_float4(a.x + b.x, a.y + b.y, a.z + b.z, a.w + b.w);
}
__device__ __forceinline__ float4 f4sub(const float4& a, const float4& b) {
  return make_float4(a.x - b.x, a.y - b.y, a.z - b.z, a.w - b.w);
}

__global__ __launch_bounds__(NTHR) void ssim_main(
    const float* __restrict__ g1, const float* __restrict__ g2,
    double* __restrict__ ws) {
  __shared__ float4 Qe[2][NTHR];         // [buf][thread] quad of col 2T
  __shared__ float4 Qo[2][NTHR];         // [buf][thread] quad of col 2T+1
  __shared__ float red[NTHR];

  const int T = threadIdx.x;             // 0..255; owns cols 2T, 2T+1
  // XCD-pinned band-major: img%8 == blockIdx%8
  const int xcd   = blockIdx.x & 7;
  const int q     = blockIdx.x >> 3;     // 0..191
  const int g     = q % (NIMG / 8);      // 0..5  (image within XCD, fast)
  const int strip = q / (NIMG / 8);      // 0..31 (band, slow)
  const int img   = g * 8 + xcd;         // 0..47
  const int b     = img / CHAN;

  const int r0 = strip * RPS;
  const int r1 = min(r0 + RPS, HO);      // row counts 16 or 6: always even
  const int c0 = 2 * T;

  const float* __restrict__ p1 = g1 + (size_t)img * HDIM * WDIM + c0;
  const float* __restrict__ p2 = g2 + (size_t)img * HDIM * WDIM + c0;

  // vertical sliding column sums for cols 2T (index 0) and 2T+1 (index 1)
  float a1x = 0, a1y = 0, a2x = 0, a2y = 0;
  float apx = 0, apy = 0, aqx = 0, aqy = 0;

  float2 n0u, n0v, n1u, n1v, o0u, o0v, o1u, o1v;   // NEW 2-deep, OLD 2-deep

  auto LDp = [&](float2& u, float2& v, int row) {
    u = *(const float2*)(p1 + (size_t)row * WDIM);
    v = *(const float2*)(p2 + (size_t)row * WDIM);
  };
  auto ACC = [&](const float2& u, const float2& v) {
    a1x += u.x;  a2x += v.x;
    apx = fmaf(u.x, v.x, apx);
    aqx = fmaf(u.x, u.x, aqx);  aqx = fmaf(v.x, v.x, aqx);
    a1y += u.y;  a2y += v.y;
    apy = fmaf(u.y, v.y, apy);
    aqy = fmaf(u.y, u.y, aqy);  aqy = fmaf(v.y, v.y, aqy);
  };
  auto SUB = [&](const float2& u, const float2& v) {
    a1x -= u.x;  a2x -= v.x;
    apx = fmaf(u.x, -v.x, apx);
    aqx = fmaf(u.x, -u.x, aqx);  aqx = fmaf(v.x, -v.x, aqx);
    a1y -= u.y;  a2y -= v.y;
    apy = fmaf(u.y, -v.y, apy);
    aqy = fmaf(u.y, -u.y, aqy);  aqy = fmaf(v.y, -v.y, aqy);
  };

  // ---- warm-up: accumulate rows r0..r0+9, 2-deep pipeline ----
  // (max row touched: r0+11 = 507 at the last strip; in-bounds)
  LDp(n0u, n0v, r0);
  LDp(n1u, n1v, r0 + 1);
#pragma unroll
  for (int k = 0; k < 5; ++k) {
    ACC(n0u, n0v);  LDp(n0u, n0v, r0 + 2 * k + 2);
    ACC(n1u, n1v);  LDp(n1u, n1v, r0 + 2 * k + 3);
  }
  // accumulated rows r0..r0+9; n0 = r0+10, n1 = r0+11
  LDp(o0u, o0v, r0);
  LDp(o1u, o1v, r0 + 1);

  float acc = 0.f;

  auto SSIM2 = [&](const float4& W, bool live) {
    // W = {w1, w2, wp, wq}; scale-folded (121^4 cancels in n/d)
    float s12 = W.x * W.y;
    float msq = fmaf(W.x, W.x, W.y * W.y);
    float N1  = fmaf(2.f, s12, K1);
    float N2  = fmaf(2.f, fmaf(W2F, W.z, -s12), K2);
    float D1  = msq + K1;
    float D2  = fmaf(W2F, W.w, -msq) + K2;
    float val = (N1 * N2) * __builtin_amdgcn_rcpf(D1 * D2);
    if (live) acc += val;
  };

  auto STEP = [&](float2& nu, float2& nv, float2& ou, float2& ov,
                  int rr, int pb) {
    ACC(nu, nv);                          // window = rows [rr, rr+10]
    LDp(nu, nv, min(rr + 12, HDIM - 1));  // NEW for STEP rr+2

    Qe[pb][T] = make_float4(a1x, a2x, apx, aqx);
    Qo[pb][T] = make_float4(a1y, a2y, apy, aqy);
    asm volatile("s_waitcnt lgkmcnt(0)\n\ts_barrier" ::: "memory");

    // halo quads: cols 2(T+j) and 2(T+j)+1, j=0..5 (clamped: masked cols)
    const int i1 = min(T + 1, NTHR - 1), i2 = min(T + 2, NTHR - 1),
              i3 = min(T + 3, NTHR - 1), i4 = min(T + 4, NTHR - 1),
              i5 = min(T + 5, NTHR - 1);
    float4 e0 = Qe[pb][T],  oq0 = Qo[pb][T];
    float4 e1 = Qe[pb][i1], oq1 = Qo[pb][i1];
    float4 e2 = Qe[pb][i2], oq2 = Qo[pb][i2];
    float4 e3 = Qe[pb][i3], oq3 = Qo[pb][i3];
    float4 e4 = Qe[pb][i4], oq4 = Qo[pb][i4];
    float4 e5 = Qe[pb][i5], oq5 = Qo[pb][i5];

    // W(2T) = (e0+o0)+(e1+o1)+(e2+o2)+(e3+o3)+(e4+o4)+e5
    float4 W0 = f4add(f4add(f4add(f4add(e0, oq0), f4add(e1, oq1)),
                            f4add(f4add(e2, oq2), f4add(e3, oq3))),
                      f4add(f4add(e4, oq4), e5));
    // W(2T+1) = W(2T) - e0 + o5
    float4 W1 = f4add(f4sub(W0, e0), oq5);

    SSIM2(W0, c0 < WO);
    SSIM2(W1, c0 + 1 < WO);

    SUB(ou, ov);                          // remove row rr
    LDp(ou, ov, min(rr + 2, HDIM - 1));   // OLD for STEP rr+2 (L2 hit)
  };

  // ---- main loop: rows in pairs (row counts are even: 16 or 6) ----
  for (int r = r0; r < r1; r += 2) {
    STEP(n0u, n0v, o0u, o0v, r,     0);
    STEP(n1u, n1v, o1u, o1v, r + 1, 1);
  }

  // ---- block reduction (cold), banked double atomic ----
  __syncthreads();
  red[T] = acc;
  __syncthreads();
#pragma unroll
  for (int s = NTHR / 2; s > 0; s >>= 1) {
    if (T < s) red[T] += red[T + s];
    __syncthreads();
  }
  if (T == 0)
    atomicAdd(&ws[b * NBANK + (blockIdx.x & (NBANK - 1))], (double)red[0]);
}

__global__ void ssim_finalize(const double* __restrict__ ws,
                              float* __restrict__ out) {
  int i = threadIdx.x;
  if (i < BATCH) {
    double s = 0.0;
#pragma unroll
    for (int k = 0; k < NBANK; ++k) s += ws[i * NBANK + k];
    out[i] = (float)(1.0 - s / ((double)CHAN * HO * WO));
  }
}

extern "C" void kernel_launch(void* const* d_in, const int* in_sizes, int n_in,
                              void* d_out, int out_size, void* d_ws,
                              size_t ws_size, hipStream_t stream) {
  const float* img1 = (const float*)d_in[0];
  const float* img2 = (const float*)d_in[1];
  float* out = (float*)d_out;
  double* ws = (double*)d_ws;

  hipMemsetAsync(d_ws, 0, BATCH * NBANK * sizeof(double), stream);
  ssim_main<<<dim3(NBLK), NTHR, 0, stream>>>(img1, img2, ws);
  ssim_finalize<<<1, 64, 0, stream>>>(ws, out);
}

// Round 22
// 49.258 us; speedup vs baseline: 1.2060x; 1.0496x over previous
//
#include <hip/hip_runtime.h>

// SSIM loss, fused. in: f32 (16,3,512,512) x2; out: f32[16].
//
// r22 = r21 (cooperative 256-thr blocks, occupancy 40.6%, VGPR 44) with
// the LDS op count cut 14 -> 8 b128 per thread-row via pair-sum algebra:
//   publish P[T] = E[T]+O[T] (quad pair-sum) and E[T] (even-col quad);
//   W(2T)   = P[T](regs)+P[T+1]+P[T+2]+P[T+3]+P[T+4]+E[T+5]   (5 reads)
//   W(2T+1) = W(2T) - E[T](regs) + (P[T+5]-E[T+5])            (1 read)
// r21's accounting: LDS pipe ~27us of 47us (dominant). This cuts it to
// ~15us, under the VALU (~17us) and HBM (~20us) envelopes.
//  * 2 cols/thread, 256 thr/block, 1536 blocks, XCD-pinned band-major.
//  * Double-buffered QP/QE + ONE raw (lgkmcnt(0); s_barrier) per row
//    (r3/r21 race argument: reads of buf p at row r complete before that
//    thread's barrier r+1; next write to p is at r+2, after barrier r+1).
//  * NEW 2-deep + OLD 2-deep register row pipeline; scale-folded SSIM;
//    banked double atomics + finalize.

namespace {
constexpr int BATCH = 16;
constexpr int CHAN  = 3;
constexpr int HDIM  = 512;
constexpr int WDIM  = 512;
constexpr int WIN   = 11;
constexpr int HO    = HDIM - WIN + 1;   // 502
constexpr int WO    = WDIM - WIN + 1;   // 502
constexpr int RPS   = 16;
constexpr int NSTRIPS = 32;             // strip31: rows 496..501 (6 rows)
constexpr int NTHR  = 256;
constexpr int NIMG  = BATCH * CHAN;     // 48
constexpr int NBLK  = NIMG * NSTRIPS;   // 1536
constexpr int NBANK = 16;
// scale-folded constants: C*121^2 (121^4 cancels in n/d)
constexpr float K1 = 6.5025f  * 14641.0f;
constexpr float K2 = 58.5225f * 14641.0f;
constexpr float W2F = 121.0f;
}

__device__ __forceinline__ float4 f4add(const float4& a, const float4& b) {
  return make_float4(a.x + b.x, a.y + b.y, a.z + b.z, a.w + b.w);
}
__device__ __forceinline__ float4 f4sub(const float4& a, const float4& b) {
  return make_float4(a.x - b.x, a.y - b.y, a.z - b.z, a.w - b.w);
}

__global__ __launch_bounds__(NTHR) void ssim_main(
    const float* __restrict__ g1, const float* __restrict__ g2,
    double* __restrict__ ws) {
  __shared__ float4 QP[2][NTHR];         // [buf][T]: pair-sum quad
  __shared__ float4 QE[2][NTHR];         // [buf][T]: even-col quad
  __shared__ float red[NTHR];

  const int T = threadIdx.x;             // 0..255; owns cols 2T, 2T+1
  // XCD-pinned band-major: img%8 == blockIdx%8
  const int xcd   = blockIdx.x & 7;
  const int q     = blockIdx.x >> 3;     // 0..191
  const int g     = q % (NIMG / 8);      // 0..5  (image within XCD, fast)
  const int strip = q / (NIMG / 8);      // 0..31 (band, slow)
  const int img   = g * 8 + xcd;         // 0..47
  const int b     = img / CHAN;

  const int r0 = strip * RPS;
  const int r1 = min(r0 + RPS, HO);      // row counts 16 or 6: always even
  const int c0 = 2 * T;

  const float* __restrict__ p1 = g1 + (size_t)img * HDIM * WDIM + c0;
  const float* __restrict__ p2 = g2 + (size_t)img * HDIM * WDIM + c0;

  // vertical sliding column sums for cols 2T (x) and 2T+1 (y)
  float a1x = 0, a1y = 0, a2x = 0, a2y = 0;
  float apx = 0, apy = 0, aqx = 0, aqy = 0;

  float2 n0u, n0v, n1u, n1v, o0u, o0v, o1u, o1v;   // NEW 2-deep, OLD 2-deep

  auto LDp = [&](float2& u, float2& v, int row) {
    u = *(const float2*)(p1 + (size_t)row * WDIM);
    v = *(const float2*)(p2 + (size_t)row * WDIM);
  };
  auto ACC = [&](const float2& u, const float2& v) {
    a1x += u.x;  a2x += v.x;
    apx = fmaf(u.x, v.x, apx);
    aqx = fmaf(u.x, u.x, aqx);  aqx = fmaf(v.x, v.x, aqx);
    a1y += u.y;  a2y += v.y;
    apy = fmaf(u.y, v.y, apy);
    aqy = fmaf(u.y, u.y, aqy);  aqy = fmaf(v.y, v.y, aqy);
  };
  auto SUB = [&](const float2& u, const float2& v) {
    a1x -= u.x;  a2x -= v.x;
    apx = fmaf(u.x, -v.x, apx);
    aqx = fmaf(u.x, -u.x, aqx);  aqx = fmaf(v.x, -v.x, aqx);
    a1y -= u.y;  a2y -= v.y;
    apy = fmaf(u.y, -v.y, apy);
    aqy = fmaf(u.y, -u.y, aqy);  aqy = fmaf(v.y, -v.y, aqy);
  };

  // ---- warm-up: accumulate rows r0..r0+9, 2-deep pipeline ----
  // (max row touched: r0+11 = 507 at the last strip; in-bounds)
  LDp(n0u, n0v, r0);
  LDp(n1u, n1v, r0 + 1);
#pragma unroll
  for (int k = 0; k < 5; ++k) {
    ACC(n0u, n0v);  LDp(n0u, n0v, r0 + 2 * k + 2);
    ACC(n1u, n1v);  LDp(n1u, n1v, r0 + 2 * k + 3);
  }
  // accumulated rows r0..r0+9; n0 = r0+10, n1 = r0+11
  LDp(o0u, o0v, r0);
  LDp(o1u, o1v, r0 + 1);

  float acc = 0.f;

  auto SSIM2 = [&](const float4& W, bool live) {
    // W = {w1, w2, wp, wq}; scale-folded (121^4 cancels in n/d)
    float s12 = W.x * W.y;
    float msq = fmaf(W.x, W.x, W.y * W.y);
    float N1  = fmaf(2.f, s12, K1);
    float N2  = fmaf(2.f, fmaf(W2F, W.z, -s12), K2);
    float D1  = msq + K1;
    float D2  = fmaf(W2F, W.w, -msq) + K2;
    float val = (N1 * N2) * __builtin_amdgcn_rcpf(D1 * D2);
    if (live) acc += val;
  };

  auto STEP = [&](float2& nu, float2& nv, float2& ou, float2& ov,
                  int rr, int pb) {
    ACC(nu, nv);                          // window = rows [rr, rr+10]
    LDp(nu, nv, min(rr + 12, HDIM - 1));  // NEW for STEP rr+2

    // own quads (registers): E = even col; P = pair sum
    const float4 Eq = make_float4(a1x, a2x, apx, aqx);
    const float4 Pq = make_float4(a1x + a1y, a2x + a2y,
                                  apx + apy, aqx + aqy);
    QP[pb][T] = Pq;
    QE[pb][T] = Eq;
    asm volatile("s_waitcnt lgkmcnt(0)\n\ts_barrier" ::: "memory");

    // 6 halo reads (clamped lanes feed masked cols >= 502)
    const int i1 = min(T + 1, NTHR - 1), i2 = min(T + 2, NTHR - 1),
              i3 = min(T + 3, NTHR - 1), i4 = min(T + 4, NTHR - 1),
              i5 = min(T + 5, NTHR - 1);
    float4 P1 = QP[pb][i1], P2 = QP[pb][i2], P3 = QP[pb][i3],
           P4 = QP[pb][i4], P5 = QP[pb][i5];
    float4 E5 = QE[pb][i5];

    // W(2T) = Pq + P1 + P2 + P3 + P4 + E5
    float4 W0 = f4add(f4add(f4add(Pq, P1), f4add(P2, P3)),
                      f4add(P4, E5));
    // W(2T+1) = W(2T) - Eq + (P5 - E5)
    float4 W1 = f4add(f4sub(W0, Eq), f4sub(P5, E5));

    SSIM2(W0, c0 < WO);
    SSIM2(W1, c0 + 1 < WO);

    SUB(ou, ov);                          // remove row rr
    LDp(ou, ov, min(rr + 2, HDIM - 1));   // OLD for STEP rr+2 (L2 hit)
  };

  // ---- main loop: rows in pairs (row counts are even: 16 or 6) ----
  for (int r = r0; r < r1; r += 2) {
    STEP(n0u, n0v, o0u, o0v, r,     0);
    STEP(n1u, n1v, o1u, o1v, r + 1, 1);
  }

  // ---- block reduction (cold), banked double atomic ----
  __syncthreads();
  red[T] = acc;
  __syncthreads();
#pragma unroll
  for (int s = NTHR / 2; s > 0; s >>= 1) {
    if (T < s) red[T] += red[T + s];
    __syncthreads();
  }
  if (T == 0)
    atomicAdd(&ws[b * NBANK + (blockIdx.x & (NBANK - 1))], (double)red[0]);
}

__global__ void ssim_finalize(const double* __restrict__ ws,
                              float* __restrict__ out) {
  int i = threadIdx.x;
  if (i < BATCH) {
    double s = 0.0;
#pragma unroll
    for (int k = 0; k < NBANK; ++k) s += ws[i * NBANK + k];
    out[i] = (float)(1.0 - s / ((double)CHAN * HO * WO));
  }
}

extern "C" void kernel_launch(void* const* d_in, const int* in_sizes, int n_in,
                              void* d_out, int out_size, void* d_ws,
                              size_t ws_size, hipStream_t stream) {
  const float* img1 = (const float*)d_in[0];
  const float* img2 = (const float*)d_in[1];
  float* out = (float*)d_out;
  double* ws = (double*)d_ws;

  hipMemsetAsync(d_ws, 0, BATCH * NBANK * sizeof(double), stream);
  ssim_main<<<dim3(NBLK), NTHR, 0, stream>>>(img1, img2, ws);
  ssim_finalize<<<1, 64, 0, stream>>>(ws, out);
}

// Round 23
// 48.107 us; speedup vs baseline: 1.2349x; 1.0239x over previous
//
#include <hip/hip_runtime.h>

// SSIM loss, fused. in: f32 (16,3,512,512) x2; out: f32[16].
//
// r23 = r22 (cooperative 256-thr blocks, occ 44.7%, VGPR 36, 8 b128/
// thread-row pair-sum scheme) with TWO ROWS FUSED PER BARRIER:
//  * per pair: ACC(n0)->publish row r; SUB(o0); ACC(n1)->publish row r+1;
//    SUB(o1); ALL 8 global refills issue (vmcnt - they cross the barrier);
//    ONE (lgkmcnt(0); s_barrier); then both rows' halo reads + SSIM are
//    independent post-barrier work (row r+1's ds_reads hide under row r's
//    window math). 8 barriers/strip instead of 16.
//  * Buffers QP/QE[parity][rowpair][256] (32 KB). Race-safe: buffer set p
//    is rewritten 2 barriers after its reads; lgkmcnt(0) inside each
//    barrier pins read completion before the next write can start.
//  * Own quads (Pq0,Eq0,Pq1,Eq1) live in registers across the barrier.
//  * Window algebra per row (r22-proven):
//      W(2T)   = Pq + P[T+1]+P[T+2]+P[T+3]+P[T+4] + E[T+5]
//      W(2T+1) = W(2T) - Eq + (P[T+5]-E[T+5])
//  * Reduction reuses QP (LDS stays exactly 32 KB). Scale-folded SSIM,
//    XCD-pinned band-major mapping, banked double atomics + finalize.

namespace {
constexpr int BATCH = 16;
constexpr int CHAN  = 3;
constexpr int HDIM  = 512;
constexpr int WDIM  = 512;
constexpr int WIN   = 11;
constexpr int HO    = HDIM - WIN + 1;   // 502
constexpr int WO    = WDIM - WIN + 1;   // 502
constexpr int RPS   = 16;
constexpr int NSTRIPS = 32;             // strip31: rows 496..501 (6 rows)
constexpr int NTHR  = 256;
constexpr int NIMG  = BATCH * CHAN;     // 48
constexpr int NBLK  = NIMG * NSTRIPS;   // 1536
constexpr int NBANK = 16;
// scale-folded constants: C*121^2 (121^4 cancels in n/d)
constexpr float K1 = 6.5025f  * 14641.0f;
constexpr float K2 = 58.5225f * 14641.0f;
constexpr float W2F = 121.0f;
}

__device__ __forceinline__ float4 f4add(const float4& a, const float4& b) {
  return make_float4(a.x + b.x, a.y + b.y, a.z + b.z, a.w + b.w);
}
__device__ __forceinline__ float4 f4sub(const float4& a, const float4& b) {
  return make_float4(a.x - b.x, a.y - b.y, a.z - b.z, a.w - b.w);
}

__global__ __launch_bounds__(NTHR) void ssim_main(
    const float* __restrict__ g1, const float* __restrict__ g2,
    double* __restrict__ ws) {
  __shared__ float4 QP[2][2][NTHR];      // [parity][row-in-pair][T]: pair-sum
  __shared__ float4 QE[2][2][NTHR];      // [parity][row-in-pair][T]: even col

  const int T = threadIdx.x;             // 0..255; owns cols 2T, 2T+1
  // XCD-pinned band-major: img%8 == blockIdx%8
  const int xcd   = blockIdx.x & 7;
  const int q     = blockIdx.x >> 3;     // 0..191
  const int g     = q % (NIMG / 8);      // 0..5  (image within XCD, fast)
  const int strip = q / (NIMG / 8);      // 0..31 (band, slow)
  const int img   = g * 8 + xcd;         // 0..47
  const int b     = img / CHAN;

  const int r0 = strip * RPS;
  const int r1 = min(r0 + RPS, HO);      // row counts 16 or 6: always even
  const int c0 = 2 * T;

  const float* __restrict__ p1 = g1 + (size_t)img * HDIM * WDIM + c0;
  const float* __restrict__ p2 = g2 + (size_t)img * HDIM * WDIM + c0;

  // vertical sliding column sums for cols 2T (x) and 2T+1 (y)
  float a1x = 0, a1y = 0, a2x = 0, a2y = 0;
  float apx = 0, apy = 0, aqx = 0, aqy = 0;

  float2 n0u, n0v, n1u, n1v, o0u, o0v, o1u, o1v;   // NEW 2-deep, OLD 2-deep

  auto LDp = [&](float2& u, float2& v, int row) {
    u = *(const float2*)(p1 + (size_t)row * WDIM);
    v = *(const float2*)(p2 + (size_t)row * WDIM);
  };
  auto ACC = [&](const float2& u, const float2& v) {
    a1x += u.x;  a2x += v.x;
    apx = fmaf(u.x, v.x, apx);
    aqx = fmaf(u.x, u.x, aqx);  aqx = fmaf(v.x, v.x, aqx);
    a1y += u.y;  a2y += v.y;
    apy = fmaf(u.y, v.y, apy);
    aqy = fmaf(u.y, u.y, aqy);  aqy = fmaf(v.y, v.y, aqy);
  };
  auto SUB = [&](const float2& u, const float2& v) {
    a1x -= u.x;  a2x -= v.x;
    apx = fmaf(u.x, -v.x, apx);
    aqx = fmaf(u.x, -u.x, aqx);  aqx = fmaf(v.x, -v.x, aqx);
    a1y -= u.y;  a2y -= v.y;
    apy = fmaf(u.y, -v.y, apy);
    aqy = fmaf(u.y, -u.y, aqy);  aqy = fmaf(v.y, -v.y, aqy);
  };

  // ---- warm-up: accumulate rows r0..r0+9, 2-deep pipeline ----
  // (max row touched: r0+11 = 507 at the last strip; in-bounds)
  LDp(n0u, n0v, r0);
  LDp(n1u, n1v, r0 + 1);
#pragma unroll
  for (int k = 0; k < 5; ++k) {
    ACC(n0u, n0v);  LDp(n0u, n0v, r0 + 2 * k + 2);
    ACC(n1u, n1v);  LDp(n1u, n1v, r0 + 2 * k + 3);
  }
  // accumulated rows r0..r0+9; n0 = r0+10, n1 = r0+11
  LDp(o0u, o0v, r0);
  LDp(o1u, o1v, r0 + 1);

  float acc = 0.f;

  auto SSIM2 = [&](const float4& W, bool live) {
    // W = {w1, w2, wp, wq}; scale-folded (121^4 cancels in n/d)
    float s12 = W.x * W.y;
    float msq = fmaf(W.x, W.x, W.y * W.y);
    float N1  = fmaf(2.f, s12, K1);
    float N2  = fmaf(2.f, fmaf(W2F, W.z, -s12), K2);
    float D1  = msq + K1;
    float D2  = fmaf(W2F, W.w, -msq) + K2;
    float val = (N1 * N2) * __builtin_amdgcn_rcpf(D1 * D2);
    if (live) acc += val;
  };

  const int i1 = min(T + 1, NTHR - 1), i2 = min(T + 2, NTHR - 1),
            i3 = min(T + 3, NTHR - 1), i4 = min(T + 4, NTHR - 1),
            i5 = min(T + 5, NTHR - 1);

  auto STEP2 = [&](int r, int pb) {
    // entering: sums = rows [r, r+9]; n0=r+10, n1=r+11, o0=r, o1=r+1
    ACC(n0u, n0v);                        // sums = S_r = rows [r, r+10]
    const float4 Eq0 = make_float4(a1x, a2x, apx, aqx);
    const float4 Pq0 = make_float4(a1x + a1y, a2x + a2y,
                                   apx + apy, aqx + aqy);
    QP[pb][0][T] = Pq0;
    QE[pb][0][T] = Eq0;
    SUB(o0u, o0v);                        // - row r
    ACC(n1u, n1v);                        // sums = S_{r+1} = [r+1, r+11]
    const float4 Eq1 = make_float4(a1x, a2x, apx, aqx);
    const float4 Pq1 = make_float4(a1x + a1y, a2x + a2y,
                                   apx + apy, aqx + aqy);
    QP[pb][1][T] = Pq1;
    QE[pb][1][T] = Eq1;
    SUB(o1u, o1v);                        // - row r+1 -> exit [r+2, r+11]

    // all 8 refills issue together; vmcnt loads cross the barrier
    LDp(n0u, n0v, min(r + 12, HDIM - 1));
    LDp(n1u, n1v, min(r + 13, HDIM - 1));
    LDp(o0u, o0v, r + 2);
    LDp(o1u, o1v, r + 3);

    asm volatile("s_waitcnt lgkmcnt(0)\n\ts_barrier" ::: "memory");

    // row r windows
    {
      float4 P1 = QP[pb][0][i1], P2 = QP[pb][0][i2], P3 = QP[pb][0][i3],
             P4 = QP[pb][0][i4], P5 = QP[pb][0][i5];
      float4 E5 = QE[pb][0][i5];
      float4 W0 = f4add(f4add(f4add(Pq0, P1), f4add(P2, P3)),
                        f4add(P4, E5));
      float4 W1 = f4add(f4sub(W0, Eq0), f4sub(P5, E5));
      SSIM2(W0, c0 < WO);
      SSIM2(W1, c0 + 1 < WO);
    }
    // row r+1 windows
    {
      float4 P1 = QP[pb][1][i1], P2 = QP[pb][1][i2], P3 = QP[pb][1][i3],
             P4 = QP[pb][1][i4], P5 = QP[pb][1][i5];
      float4 E5 = QE[pb][1][i5];
      float4 W0 = f4add(f4add(f4add(Pq1, P1), f4add(P2, P3)),
                        f4add(P4, E5));
      float4 W1 = f4add(f4sub(W0, Eq1), f4sub(P5, E5));
      SSIM2(W0, c0 < WO);
      SSIM2(W1, c0 + 1 < WO);
    }
  };

  // ---- main loop: row pairs, parity-alternating buffer sets ----
  int pb = 0;
  for (int r = r0; r < r1; r += 2, pb ^= 1) STEP2(r, pb);

  // ---- block reduction (cold), reusing QP as scratch ----
  __syncthreads();
  float* red = (float*)&QP[0][0][0];
  red[T] = acc;
  __syncthreads();
#pragma unroll
  for (int s = NTHR / 2; s > 0; s >>= 1) {
    if (T < s) red[T] += red[T + s];
    __syncthreads();
  }
  if (T == 0)
    atomicAdd(&ws[b * NBANK + (blockIdx.x & (NBANK - 1))], (double)red[0]);
}

__global__ void ssim_finalize(const double* __restrict__ ws,
                              float* __restrict__ out) {
  int i = threadIdx.x;
  if (i < BATCH) {
    double s = 0.0;
#pragma unroll
    for (int k = 0; k < NBANK; ++k) s += ws[i * NBANK + k];
    out[i] = (float)(1.0 - s / ((double)CHAN * HO * WO));
  }
}

extern "C" void kernel_launch(void* const* d_in, const int* in_sizes, int n_in,
                              void* d_out, int out_size, void* d_ws,
                              size_t ws_size, hipStream_t stream) {
  const float* img1 = (const float*)d_in[0];
  const float* img2 = (const float*)d_in[1];
  float* out = (float*)d_out;
  double* ws = (double*)d_ws;

  hipMemsetAsync(d_ws, 0, BATCH * NBANK * sizeof(double), stream);
  ssim_main<<<dim3(NBLK), NTHR, 0, stream>>>(img1, img2, ws);
  ssim_finalize<<<1, 64, 0, stream>>>(ws, out);
}